// Round 13
// baseline (4038.411 us; speedup 1.0000x reference)
//
#include <hip/hip_runtime.h>
#include <math.h>

namespace {

constexpr int B = 8, T = 10, C = 32, H = 128, W = 128;
constexpr int HW = H * W;            // 16384
constexpr int CHW = C * HW;          // 524288
constexpr int BHW = B * HW;
constexpr long long NSTATE = (long long)B * CHW;

constexpr float DF = 0.90483741803595952f;  // exp(-0.1)
constexpr float DL = 0.36787944117144233f;  // exp(-1.0)
constexpr float DE = 0.36787944117144233f;  // exp(-1.0)
constexpr float VE = 10.0f;
constexpr float E0 = 3.6787944117144233f;   // DE * (V_E/ALPHA_E), e-fold init

// wgt[co][ci][kh][kw] -> wtr[ci][k][co]   (9216 floats)
__global__ void k_wtr(const float* __restrict__ wgt, float* __restrict__ wtr) {
  int i = blockIdx.x * 256 + threadIdx.x;
  if (i >= C * C * 9) return;
  int ci = i / 288;
  int k = (i / 32) % 9;
  int co = i & 31;
  wtr[i] = wgt[co * 288 + ci * 9 + k];
}

// t=0: y_prev=0 -> conv=0, l=0, u=f. Writes f, e_used(1), out[0], l-plane.
// (No s plane: later steps compute the chansum from their staged y tile.)
__launch_bounds__(256, 2)
__global__ void k_step0(const float* __restrict__ x, const float* __restrict__ bias,
                        float* __restrict__ f, float* __restrict__ e,
                        float* __restrict__ lpl, float* __restrict__ out) {
  const int tid = threadIdx.x, bid = blockIdx.x;
  const int wg = (bid & 7) * 128 + (bid >> 3);  // XCD swizzle: batch per XCD
  const int tw = wg & 7, th = (wg >> 3) & 15, b = wg >> 7;
  const int h0 = th * 8, w0 = tw * 16;
  const int g = tid >> 5, s = tid & 31;
  const int sh = s >> 2, sw = s & 3, cb = 4 * sw;
  const int gh = h0 + sh, gwc = w0 + cb;
  const float4 bc4 = *(const float4*)&bias[4 * g];
  const float bc[4] = {bc4.x, bc4.y, bc4.z, bc4.w};

#pragma unroll
  for (int q = 0; q < 4; ++q) {
    const int c = 4 * g + q;
    const size_t sidx = (size_t)b * CHW + (size_t)c * HW + (size_t)gh * W + gwc;
    const size_t oidx = (((size_t)b * T) * C + c) * (size_t)HW + (size_t)gh * W + gwc;
    float4 x4 = *(const float4*)(x + oidx);
    float xr[4] = {x4.x, x4.y, x4.z, x4.w};
    float fo[4], eo[4], yn[4];
#pragma unroll
    for (int p = 0; p < 4; ++p) {
      float fn = bc[q] + xr[p];                  // DF*0 + conv(0) + bias + x
      float yy = 1.f / (1.f + __expf(E0 - fn));  // u = fn (l=0)
      fo[p] = fn;
      eo[p] = DE * E0 + VE * yy;                 // e_used(1)
      yn[p] = yy;
    }
    *(float4*)(f + sidx) = make_float4(fo[0], fo[1], fo[2], fo[3]);
    *(float4*)(e + sidx) = make_float4(eo[0], eo[1], eo[2], eo[3]);
    *(float4*)(out + oidx) = make_float4(yn[0], yn[1], yn[2], yn[3]);
  }
  if (tid < 32) {
    const size_t pidx = (size_t)b * HW + (size_t)gh * W + gwc;
    *(float4*)(lpl + pidx) = make_float4(0.f, 0.f, 0.f, 0.f);  // l_1 = 0
  }
}

// Steps 1..T-1. 1024 blocks x 256 threads, tile 8x16, all 32 c_out.
// ci in 4 chunks of 8, DOUBLE-buffered LDS, ONE barrier per chunk:
//   chunk cc: commit(cc+1 -> buf nb^1) [regs prefetched at cc-1],
//             prefetch(cc+2), conv(buf nb) + chansum adds, barrier.
// Chansum (for the fixed conv's l-inc) is accumulated from the staged y
// chunks -- no global s planes, no sred reduce phase (R12 had both).
// f/e epilogue loads issued at chunk 3 (prefetch regs dead) per R12.
__launch_bounds__(256, 2)
__global__ void k_step(const float* __restrict__ x, const float* __restrict__ wtr,
                       const float* __restrict__ bias, float* __restrict__ f,
                       float* __restrict__ e, float* __restrict__ lpl,
                       float* __restrict__ out, int t) {
  __shared__ float ysl[2][8][10][28];  // [buf][ci][row][slot], slot=w-(w0-4); 17920B
  __shared__ float wsl[2][8][9][32];   // [buf][ci][k][c_out]; 18432B
  __shared__ float sl[10][21];         // chansum tile (+halo); 840B

  const int tid = threadIdx.x, bid = blockIdx.x;
  const int wg = (bid & 7) * 128 + (bid >> 3);  // XCD swizzle: batch per XCD
  const int tw = wg & 7, th = (wg >> 3) & 15, b = wg >> 7;
  const int h0 = th * 8, w0 = tw * 16;
  const int g = tid >> 5, s = tid & 31;
  const int sh = s >> 2, sw = s & 3, cb = 4 * sw;
  const int gh = h0 + sh, gwc = w0 + cb;

  const float* ybase = out + ((size_t)b * T + (t - 1)) * CHW;

  // l-plane read (channel-uniform)
  float4 l4 = *(const float4*)(lpl + (size_t)b * HW + (size_t)gh * W + gwc);
  float lold[4] = {l4.x, l4.y, l4.z, l4.w};

  // y-prefetch slots (chunk-invariant address parts). 480 float4 per chunk.
  const int i0 = tid;                                  // slot 0: always valid
  const int cil0 = i0 / 60, rr0 = (i0 % 60) / 6, j0 = i0 % 6;
  const int gh0p = h0 - 1 + rr0, ws0p = w0 - 4 + 4 * j0;
  const bool ok0 = (unsigned)gh0p < (unsigned)H && (unsigned)ws0p <= (unsigned)(W - 4);
  const size_t yoff0 = (size_t)cil0 * HW + (size_t)(ok0 ? gh0p * W + ws0p : 0);
  const int i1 = tid + 256;                            // slot 1: valid if <480
  const bool use1 = i1 < 480;
  const int cil1 = (i1 / 60) & 7, rr1 = (i1 % 60) / 6, j1 = i1 % 6;
  const int gh1p = h0 - 1 + rr1, ws1p = w0 - 4 + 4 * j1;
  const bool ok1 = use1 && (unsigned)gh1p < (unsigned)H &&
                   (unsigned)ws1p <= (unsigned)(W - 4);
  const size_t yoff1 = (size_t)cil1 * HW + (size_t)(ok1 ? gh1p * W + ws1p : 0);

  const float4* const wsrc = (const float4*)wtr;       // 576 float4 per chunk

  float4 y0v, y1v, w0v, w1v, w2v;
  auto prefetch = [&](int cc) {
    const float* yb = ybase + (size_t)cc * 8 * HW;
    y0v = ok0 ? *(const float4*)(yb + yoff0) : make_float4(0.f, 0.f, 0.f, 0.f);
    y1v = ok1 ? *(const float4*)(yb + yoff1) : make_float4(0.f, 0.f, 0.f, 0.f);
    const float4* wb = wsrc + cc * 576;
    w0v = wb[tid];
    w1v = wb[tid + 256];
    w2v = (tid < 64) ? wb[tid + 512] : make_float4(0.f, 0.f, 0.f, 0.f);
  };
  auto commit = [&](int nb) {  // rows stride 28 floats = 112B (16B-divisible)
    *(float4*)&ysl[nb][cil0][rr0][4 * j0] = y0v;
    if (use1) *(float4*)&ysl[nb][cil1][rr1][4 * j1] = y1v;
    float4* wl = (float4*)&wsl[nb][0][0][0];
    wl[tid] = w0v;
    wl[tid + 256] = w1v;
    if (tid < 64) wl[tid + 512] = w2v;
  };

  prefetch(0);
  commit(0);
  prefetch(1);
  __syncthreads();  // buf0 visible

  float acc[4][4] = {};
  float scol = 0.f;                       // chansum accumulator (tid<180)
  const int srr = tid / 18, scl = tid % 18;
  float4 fq4[4], eq4[4];

#pragma unroll 1
  for (int cc = 0; cc < 4; ++cc) {
    const int nb = cc & 1;
    if (cc < 3) commit(nb ^ 1);      // chunk cc+1 -> other buffer (regs ready)
    if (cc < 2) prefetch(cc + 2);    // depth-2 prefetch, lands during conv(s)
    if (cc == 3) {                   // prefetch regs dead: early f/e loads
#pragma unroll
      for (int q = 0; q < 4; ++q) {
        const size_t sidx =
            (size_t)b * CHW + (size_t)(4 * g + q) * HW + (size_t)gh * W + gwc;
        fq4[q] = *(const float4*)(f + sidx);
        eq4[q] = *(const float4*)(e + sidx);
      }
    }
    // conv on buf nb
#pragma unroll
    for (int cil = 0; cil < 8; ++cil) {
#pragma unroll
      for (int kh = 0; kh < 3; ++kh) {
        const float* rowp = &ysl[nb][cil][sh + kh][0];
        float2 a2 = *(const float2*)(rowp + cb + 2);   // slots cb+2,cb+3
        float4 m4 = *(const float4*)(rowp + cb + 4);   // slots cb+4..cb+7
        float2 z2 = *(const float2*)(rowp + cb + 8);   // slots cb+8,cb+9
        const float yrow[6] = {a2.y, m4.x, m4.y, m4.z, m4.w, z2.x};
#pragma unroll
        for (int kw = 0; kw < 3; ++kw) {
          float4 wk = *(const float4*)&wsl[nb][cil][3 * kh + kw][4 * g];
          const float wq[4] = {wk.x, wk.y, wk.z, wk.w};
#pragma unroll
          for (int q = 0; q < 4; ++q)
#pragma unroll
            for (int p = 0; p < 4; ++p)
              acc[q][p] = fmaf(wq[q], yrow[p + kw], acc[q][p]);
        }
      }
    }
    // chansum rides the staged chunk: 8 adds for the 180 sl positions
    if (tid < 180) {
      const float* yb = &ysl[nb][0][srr][scl + 3];
#pragma unroll
      for (int ci = 0; ci < 8; ++ci) scol += yb[ci * 280];
    }
    __syncthreads();  // one barrier per chunk (dbuf ordering)
  }

  // finalize chansum tile, then l-inc
  if (tid < 180) sl[srr][scl] = scol;
  __syncthreads();
  float lnew[4];
#pragma unroll
  for (int p = 0; p < 4; ++p) {
    const int c0 = cb + p;
    float linc =
        0.5f * (sl[sh][c0] + sl[sh][c0 + 2] + sl[sh + 2][c0] + sl[sh + 2][c0 + 2]) +
        sl[sh][c0 + 1] + sl[sh + 2][c0 + 1] + sl[sh + 1][c0] + sl[sh + 1][c0 + 2];
    lnew[p] = DL * lold[p] + linc;
  }

  // epilogue: f/e update (e-fold), out write
  const float4 bc4 = *(const float4*)&bias[4 * g];
  const float bc[4] = {bc4.x, bc4.y, bc4.z, bc4.w};
#pragma unroll
  for (int q = 0; q < 4; ++q) {
    const int c = 4 * g + q;
    const size_t sidx = (size_t)b * CHW + (size_t)c * HW + (size_t)gh * W + gwc;
    const size_t oidx = (((size_t)b * T + t) * C + c) * (size_t)HW + (size_t)gh * W + gwc;
    float4 x4 = *(const float4*)(x + oidx);
    float fr[4] = {fq4[q].x, fq4[q].y, fq4[q].z, fq4[q].w};
    float er[4] = {eq4[q].x, eq4[q].y, eq4[q].z, eq4[q].w};
    float xr[4] = {x4.x, x4.y, x4.z, x4.w};
    float fo[4], eo[4], yn[4];
#pragma unroll
    for (int p = 0; p < 4; ++p) {
      float fn = DF * fr[p] + acc[q][p] + bc[q] + xr[p];
      float u = fmaf(0.5f * fn, lnew[p], fn);
      float yy = 1.f / (1.f + __expf(er[p] - u));
      fo[p] = fn;
      eo[p] = DE * er[p] + VE * yy;  // e_used(t+1)
      yn[p] = yy;
    }
    *(float4*)(f + sidx) = make_float4(fo[0], fo[1], fo[2], fo[3]);
    *(float4*)(e + sidx) = make_float4(eo[0], eo[1], eo[2], eo[3]);
    *(float4*)(out + oidx) = make_float4(yn[0], yn[1], yn[2], yn[3]);
  }
  if (tid < 32) {  // g==0 threads span the tile: store l-plane
    const size_t pidx = (size_t)b * HW + (size_t)gh * W + gwc;
    *(float4*)(lpl + pidx) = make_float4(lnew[0], lnew[1], lnew[2], lnew[3]);
  }
}

}  // namespace

extern "C" void kernel_launch(void* const* d_in, const int* in_sizes, int n_in,
                              void* d_out, int out_size, void* d_ws, size_t ws_size,
                              hipStream_t stream) {
  (void)in_sizes; (void)n_in; (void)out_size; (void)ws_size;
  const float* x = (const float*)d_in[0];     // (B,T,C,H,W)
  const float* wgt = (const float*)d_in[1];   // (C,C,3,3)
  const float* bias = (const float*)d_in[2];  // (C,)
  float* out = (float*)d_out;                 // (B,T,C,H,W)

  float* ws = (float*)d_ws;
  float* f = ws;                    // NSTATE
  float* e = f + NSTATE;            // NSTATE
  float* lpl = e + NSTATE;          // BHW (l is channel-uniform)
  float* wtr = lpl + BHW;           // 9216

  k_wtr<<<36, 256, 0, stream>>>(wgt, wtr);
  k_step0<<<1024, 256, 0, stream>>>(x, bias, f, e, lpl, out);

  for (int t = 1; t < T; ++t) {
    k_step<<<1024, 256, 0, stream>>>(x, wtr, bias, f, e, lpl, out, t);
  }
}

// Round 14
// 995.919 us; speedup vs baseline: 4.0550x; 4.0550x over previous
//
#include <hip/hip_runtime.h>
#include <math.h>

namespace {

constexpr int B = 8, T = 10, C = 32, H = 128, W = 128;
constexpr int HW = H * W;            // 16384
constexpr int CHW = C * HW;          // 524288
constexpr int BHW = B * HW;
constexpr long long NSTATE = (long long)B * CHW;

constexpr float DF = 0.90483741803595952f;  // exp(-0.1)
constexpr float DL = 0.36787944117144233f;  // exp(-1.0)
constexpr float DE = 0.36787944117144233f;  // exp(-1.0)
constexpr float VE = 10.0f;
constexpr float E0 = 3.6787944117144233f;   // DE * (V_E/ALPHA_E), e-fold init

// wgt[co][ci][kh][kw] -> wtr[ci][k][co]   (9216 floats)
__global__ void k_wtr(const float* __restrict__ wgt, float* __restrict__ wtr) {
  int i = blockIdx.x * 256 + threadIdx.x;
  if (i >= C * C * 9) return;
  int ci = i / 288;
  int k = (i / 32) % 9;
  int co = i & 31;
  wtr[i] = wgt[co * 288 + ci * 9 + k];
}

// t=0: y_prev=0 -> conv=0, l=0, u=f. Writes f, e_used(1), out[0], l-plane.
__launch_bounds__(256, 2)
__global__ void k_step0(const float* __restrict__ x, const float* __restrict__ bias,
                        float* __restrict__ f, float* __restrict__ e,
                        float* __restrict__ lpl, float* __restrict__ out) {
  const int tid = threadIdx.x, bid = blockIdx.x;
  const int wg = (bid & 7) * 128 + (bid >> 3);  // XCD swizzle
  const int tw = wg & 7, th = (wg >> 3) & 15, b = wg >> 7;
  const int h0 = th * 8, w0 = tw * 16;
  const int g = tid >> 5, s = tid & 31;
  const int sh = s >> 2, sw = s & 3, cb = 4 * sw;
  const int gh = h0 + sh, gwc = w0 + cb;
  const float4 bc4 = *(const float4*)&bias[4 * g];
  const float bc[4] = {bc4.x, bc4.y, bc4.z, bc4.w};

#pragma unroll
  for (int q = 0; q < 4; ++q) {
    const int c = 4 * g + q;
    const size_t sidx = (size_t)b * CHW + (size_t)c * HW + (size_t)gh * W + gwc;
    const size_t oidx = (((size_t)b * T) * C + c) * (size_t)HW + (size_t)gh * W + gwc;
    float4 x4 = *(const float4*)(x + oidx);
    float xr[4] = {x4.x, x4.y, x4.z, x4.w};
    float fo[4], eo[4], yn[4];
#pragma unroll
    for (int p = 0; p < 4; ++p) {
      float fn = bc[q] + xr[p];                  // DF*0 + conv(0) + bias + x
      float yy = 1.f / (1.f + __expf(E0 - fn));  // u = fn (l=0)
      fo[p] = fn;
      eo[p] = DE * E0 + VE * yy;                 // e_used(1)
      yn[p] = yy;
    }
    *(float4*)(f + sidx) = make_float4(fo[0], fo[1], fo[2], fo[3]);
    *(float4*)(e + sidx) = make_float4(eo[0], eo[1], eo[2], eo[3]);
    *(float4*)(out + oidx) = make_float4(yn[0], yn[1], yn[2], yn[3]);
  }
  if (tid < 32) {
    const size_t pidx = (size_t)b * HW + (size_t)gh * W + gwc;
    *(float4*)(lpl + pidx) = make_float4(0.f, 0.f, 0.f, 0.f);  // l_1 = 0
  }
}

// Steps 1..T-1. 512 blocks x 256 threads, tile 8x32, wave = co-group (8 co).
// Weights: NO LDS -- wave-uniform addresses (readfirstlane base) -> scalar
// loads (s_load) from L1/L2-hot wtr. LDS carries only the y tile, double-
// buffered, commit-AFTER-conv with depth-1 prefetch (R12's register profile,
// R13's depth-2 bug avoided) -> ONE barrier per chunk.
// Chansum for the fixed conv accumulated from the staged y tile (no s planes).
__launch_bounds__(256, 2)
__global__ void k_step(const float* __restrict__ x, const float* __restrict__ wtr,
                       const float* __restrict__ bias, float* __restrict__ f,
                       float* __restrict__ e, float* __restrict__ lpl,
                       float* __restrict__ out, int t) {
  __shared__ float ysl[2][8][10][40];  // [buf][ci][row][slot], slot=w-(w0-4); 25.6KB
  __shared__ float sl[10][35];         // chansum tile (+halo)

  const int tid = threadIdx.x, bid = blockIdx.x;
  const int wg = (bid & 7) * 64 + (bid >> 3);  // XCD swizzle (512 = 8 XCD x 64)
  const int tw = wg & 3, th = (wg >> 2) & 15, b = wg >> 6;
  const int h0 = th * 8, w0 = tw * 32;
  const int s = tid & 63;
  const int sh = s >> 3, sw = s & 7, cb = 4 * sw;
  const int gh = h0 + sh, gwc = w0 + cb;
  const int cob = __builtin_amdgcn_readfirstlane((tid >> 6) * 8);  // wave co-base

  const float* ybase = out + ((size_t)b * T + (t - 1)) * CHW;

  // l-plane read (channel-uniform)
  float4 l4 = *(const float4*)(lpl + (size_t)b * HW + (size_t)gh * W + gwc);
  float lold[4] = {l4.x, l4.y, l4.z, l4.w};

  // y slot geometry: 800 float4/chunk, sets A..D (D only tid<32)
  const int iA = tid, iB = tid + 256, iC = tid + 512, iD = tid + 768;
  const int cilA = iA / 100, rrA = (iA % 100) / 10, jA = iA % 10;
  const int cilB = iB / 100, rrB = (iB % 100) / 10, jB = iB % 10;
  const int cilC = iC / 100, rrC = (iC % 100) / 10, jC = iC % 10;
  const int cilD = (iD / 100) & 7, rrD = (iD % 100) / 10, jD = iD % 10;
  const int ghA = h0 - 1 + rrA, wsA = w0 - 4 + 4 * jA;
  const int ghB = h0 - 1 + rrB, wsB = w0 - 4 + 4 * jB;
  const int ghC = h0 - 1 + rrC, wsC = w0 - 4 + 4 * jC;
  const int ghD = h0 - 1 + rrD, wsD = w0 - 4 + 4 * jD;
  const bool okA = (unsigned)ghA < (unsigned)H && (unsigned)wsA <= (unsigned)(W - 4);
  const bool okB = (unsigned)ghB < (unsigned)H && (unsigned)wsB <= (unsigned)(W - 4);
  const bool okC = (unsigned)ghC < (unsigned)H && (unsigned)wsC <= (unsigned)(W - 4);
  const bool okD = iD < 800 && (unsigned)ghD < (unsigned)H &&
                   (unsigned)wsD <= (unsigned)(W - 4);
  const size_t yoA = (size_t)cilA * HW + (size_t)(okA ? ghA * W + wsA : 0);
  const size_t yoB = (size_t)cilB * HW + (size_t)(okB ? ghB * W + wsB : 0);
  const size_t yoC = (size_t)cilC * HW + (size_t)(okC ? ghC * W + wsC : 0);
  const size_t yoD = (size_t)cilD * HW + (size_t)(okD ? ghD * W + wsD : 0);

  float4 yA, yB, yC, yD;
  auto prefetch = [&](int cc) {
    const float* yb = ybase + (size_t)cc * 8 * HW;
    yA = okA ? *(const float4*)(yb + yoA) : make_float4(0.f, 0.f, 0.f, 0.f);
    yB = okB ? *(const float4*)(yb + yoB) : make_float4(0.f, 0.f, 0.f, 0.f);
    yC = okC ? *(const float4*)(yb + yoC) : make_float4(0.f, 0.f, 0.f, 0.f);
    yD = okD ? *(const float4*)(yb + yoD) : make_float4(0.f, 0.f, 0.f, 0.f);
  };
  auto commit = [&](int nb) {
    *(float4*)&ysl[nb][cilA][rrA][4 * jA] = yA;
    *(float4*)&ysl[nb][cilB][rrB][4 * jB] = yB;
    *(float4*)&ysl[nb][cilC][rrC][4 * jC] = yC;
    if (iD < 800) *(float4*)&ysl[nb][cilD][rrD][4 * jD] = yD;
  };

  prefetch(0);
  commit(0);
  prefetch(1);
  __syncthreads();  // buf0 visible

  float acc[8][4] = {};
  // chansum accumulators: positions (rr, cl) over [10][34]
  float scA = 0.f, scB = 0.f;
  const int srA = tid / 34, scolA = tid % 34;
  const bool hasB = (tid + 256) < 340;
  const int srB = (tid + 256) / 34, scolB = (tid + 256) % 34;

#pragma unroll 1
  for (int cc = 0; cc < 4; ++cc) {
    const int nb = cc & 1;
    const float* wpc = wtr + (cc * 8) * 288 + cob;  // wave-uniform base
#pragma unroll
    for (int ci = 0; ci < 8; ++ci) {
      float yr[3][6];
#pragma unroll
      for (int kh = 0; kh < 3; ++kh) {
        const float* rowp = &ysl[nb][ci][sh + kh][0];
        float2 a2 = *(const float2*)(rowp + cb + 2);   // slots cb+2,cb+3
        float4 m4 = *(const float4*)(rowp + cb + 4);   // slots cb+4..cb+7
        float2 z2 = *(const float2*)(rowp + cb + 8);   // slots cb+8,cb+9
        yr[kh][0] = a2.y; yr[kh][1] = m4.x; yr[kh][2] = m4.y;
        yr[kh][3] = m4.z; yr[kh][4] = m4.w; yr[kh][5] = z2.x;
      }
      const float* wci = wpc + ci * 288;
#pragma unroll
      for (int k = 0; k < 9; ++k) {
        const int kh = k / 3, kw = k % 3;
        float4 wa = *(const float4*)(wci + k * 32);      // uniform -> s_load
        float4 wb = *(const float4*)(wci + k * 32 + 4);  // uniform -> s_load
        const float wq[8] = {wa.x, wa.y, wa.z, wa.w, wb.x, wb.y, wb.z, wb.w};
#pragma unroll
        for (int q = 0; q < 8; ++q)
#pragma unroll
          for (int p = 0; p < 4; ++p)
            acc[q][p] = fmaf(wq[q], yr[kh][p + kw], acc[q][p]);
      }
      // chansum rides the staged chunk (1-2 b32 reads per ci)
      scA += ysl[nb][ci][srA][scolA + 3];
      if (hasB) scB += ysl[nb][ci][srB][scolB + 3];
    }
    if (cc < 3) {
      commit(nb ^ 1);                 // regs prefetched one chunk ago
      if (cc < 2) prefetch(cc + 2);   // depth-1 in flight at any time
      __syncthreads();                // one barrier per chunk (dbuf)
    }
  }

  // finalize chansum tile, then l-inc
  sl[srA][scolA] = scA;
  if (hasB) sl[srB][scolB] = scB;
  __syncthreads();
  float lnew[4];
#pragma unroll
  for (int p = 0; p < 4; ++p) {
    const int c0 = cb + p;
    float linc =
        0.5f * (sl[sh][c0] + sl[sh][c0 + 2] + sl[sh + 2][c0] + sl[sh + 2][c0 + 2]) +
        sl[sh][c0 + 1] + sl[sh + 2][c0 + 1] + sl[sh + 1][c0] + sl[sh + 1][c0 + 2];
    lnew[p] = DL * lold[p] + linc;
  }

  // epilogue: f/e update (e-fold), out write; 8 co per thread
  const float4 bcA = *(const float4*)&bias[cob];
  const float4 bcB = *(const float4*)&bias[cob + 4];
  const float bc[8] = {bcA.x, bcA.y, bcA.z, bcA.w, bcB.x, bcB.y, bcB.z, bcB.w};
#pragma unroll
  for (int q = 0; q < 8; ++q) {
    const int c = cob + q;
    const size_t sidx = (size_t)b * CHW + (size_t)c * HW + (size_t)gh * W + gwc;
    const size_t oidx = (((size_t)b * T + t) * C + c) * (size_t)HW + (size_t)gh * W + gwc;
    float4 f4 = *(const float4*)(f + sidx);
    float4 e4 = *(const float4*)(e + sidx);
    float4 x4 = *(const float4*)(x + oidx);
    float fr[4] = {f4.x, f4.y, f4.z, f4.w};
    float er[4] = {e4.x, e4.y, e4.z, e4.w};
    float xr[4] = {x4.x, x4.y, x4.z, x4.w};
    float fo[4], eo[4], yn[4];
#pragma unroll
    for (int p = 0; p < 4; ++p) {
      float fn = DF * fr[p] + acc[q][p] + bc[q] + xr[p];
      float u = fmaf(0.5f * fn, lnew[p], fn);
      float yy = 1.f / (1.f + __expf(er[p] - u));
      fo[p] = fn;
      eo[p] = DE * er[p] + VE * yy;  // e_used(t+1)
      yn[p] = yy;
    }
    *(float4*)(f + sidx) = make_float4(fo[0], fo[1], fo[2], fo[3]);
    *(float4*)(e + sidx) = make_float4(eo[0], eo[1], eo[2], eo[3]);
    *(float4*)(out + oidx) = make_float4(yn[0], yn[1], yn[2], yn[3]);
  }
  if (tid < 64) {  // wave 0 spans the whole 8x32 tile: store l-plane
    const size_t pidx = (size_t)b * HW + (size_t)gh * W + gwc;
    *(float4*)(lpl + pidx) = make_float4(lnew[0], lnew[1], lnew[2], lnew[3]);
  }
}

}  // namespace

extern "C" void kernel_launch(void* const* d_in, const int* in_sizes, int n_in,
                              void* d_out, int out_size, void* d_ws, size_t ws_size,
                              hipStream_t stream) {
  (void)in_sizes; (void)n_in; (void)out_size; (void)ws_size;
  const float* x = (const float*)d_in[0];     // (B,T,C,H,W)
  const float* wgt = (const float*)d_in[1];   // (C,C,3,3)
  const float* bias = (const float*)d_in[2];  // (C,)
  float* out = (float*)d_out;                 // (B,T,C,H,W)

  float* ws = (float*)d_ws;
  float* f = ws;                    // NSTATE
  float* e = f + NSTATE;            // NSTATE
  float* lpl = e + NSTATE;          // BHW (l is channel-uniform)
  float* wtr = lpl + BHW;           // 9216

  k_wtr<<<36, 256, 0, stream>>>(wgt, wtr);
  k_step0<<<1024, 256, 0, stream>>>(x, bias, f, e, lpl, out);

  for (int t = 1; t < T; ++t) {
    k_step<<<512, 256, 0, stream>>>(x, wtr, bias, f, e, lpl, out, t);
  }
}